// Round 10
// baseline (388.480 us; speedup 1.0000x reference)
//
#include <hip/hip_runtime.h>

// GAT self-attention: Wh = h@W; out = softmax(leaky_relu(Wh@Wh^T)) @ Wh
// N=8192, IN_F=256, OUT_F=128. adj input unused by the math.
//
// Round 10: flash occupancy 3 -> 4 blocks/CU. LDS pads replaced by XOR
// swizzle (col ^= (row&7)<<3 halves): K[64x128]+Vt[128x64]+P[4x16x64]
// = 40,960 B = 160KB/4 exactly; all access patterns hand-checked <=2-way
// bank aliasing (free). __launch_bounds__(256,4) (VGPR target 128; hand
// count ~115-120). exp2-fold: Q fragments pre-scaled by log2e (leaky_relu
// is positively homogeneous -> exact), softmax uses raw v_exp_f32.
// wprep/wh (MFMA, r9) and combine (exp2) otherwise unchanged.

#define SEQ   8192
#define DIM   128
#define IN_F  256
#define BM    64
#define BN    64
#define NSPLIT 6
#define NKT   (SEQ / BN)      // 128 key tiles total
#define LOG2E 1.4426950408889634f

typedef __attribute__((ext_vector_type(8))) _Float16 f16x8;
typedef __attribute__((ext_vector_type(4))) _Float16 f16x4;
typedef __attribute__((ext_vector_type(4))) float   floatx4;

// ---------------------------------------------------------------------------
// Kernel 0: Wt16[d][k] = (f16) W[k][d].  4096 units of (d, 8-k chunk).
// ---------------------------------------------------------------------------
__global__ __launch_bounds__(256) void wprep_kernel(
    const float* __restrict__ W, _Float16* __restrict__ Wt16) {
  int u = blockIdx.x * 256 + threadIdx.x;     // 0..4095
  int d  = u >> 5;
  int k8 = (u & 31) * 8;
  f16x8 v;
#pragma unroll
  for (int i = 0; i < 8; i++) v[i] = (_Float16)W[(size_t)(k8 + i) * DIM + d];
  *(f16x8*)&Wt16[(size_t)d * IN_F + k8] = v;
}

// ---------------------------------------------------------------------------
// Kernel 1: Wh = h @ W via mfma_f32_16x16x32_f16, dual orientation (r9).
// ---------------------------------------------------------------------------
__global__ __launch_bounds__(256) void wh_kernel(
    const float* __restrict__ h, const _Float16* __restrict__ Wt16,
    _Float16* __restrict__ Wh16, _Float16* __restrict__ WhT16) {
  const int tid  = threadIdx.x;
  const int lane = tid & 63;
  const int wave = tid >> 6;
  const int n16  = lane & 15;
  const int quad = lane >> 4;
  const int qbase = blockIdx.x * 16;

  f16x8 hf[8];
  const float* hrow = h + (size_t)(qbase + n16) * IN_F + quad * 8;
#pragma unroll
  for (int c = 0; c < 8; c++) {
    float4 a = *(const float4*)&hrow[c * 32];
    float4 b = *(const float4*)&hrow[c * 32 + 4];
    f16x8 v;
    v[0] = (_Float16)a.x; v[1] = (_Float16)a.y;
    v[2] = (_Float16)a.z; v[3] = (_Float16)a.w;
    v[4] = (_Float16)b.x; v[5] = (_Float16)b.y;
    v[6] = (_Float16)b.z; v[7] = (_Float16)b.w;
    hf[c] = v;
  }

#pragma unroll
  for (int ti = 0; ti < 2; ti++) {
    const int t = wave * 2 + ti;
    floatx4 o  = (floatx4){0.f, 0.f, 0.f, 0.f};
    floatx4 o2 = (floatx4){0.f, 0.f, 0.f, 0.f};
#pragma unroll
    for (int c = 0; c < 8; c++) {
      f16x8 wf = *(const f16x8*)&Wt16[(size_t)(t * 16 + n16) * IN_F
                                      + c * 32 + quad * 8];
      o  = __builtin_amdgcn_mfma_f32_16x16x32_f16(wf, hf[c], o,  0, 0, 0);
      o2 = __builtin_amdgcn_mfma_f32_16x16x32_f16(hf[c], wf, o2, 0, 0, 0);
    }
    f16x4 r;
    r[0] = (_Float16)o[0]; r[1] = (_Float16)o[1];
    r[2] = (_Float16)o[2]; r[3] = (_Float16)o[3];
    *(f16x4*)&Wh16[(size_t)(qbase + n16) * DIM + t * 16 + quad * 4] = r;
    f16x4 rt;
    rt[0] = (_Float16)o2[0]; rt[1] = (_Float16)o2[1];
    rt[2] = (_Float16)o2[2]; rt[3] = (_Float16)o2[3];
    *(f16x4*)&WhT16[(size_t)(t * 16 + n16) * SEQ + qbase + quad * 4] = rt;
  }
}

// ---------------------------------------------------------------------------
// Kernel 2: flash attention, swapped-QK^T. XOR-swizzled LDS, 4 blocks/CU.
// LDS: Ksh [64x128] + Vtsh [128x64] + Psh [4][16x64] = 20480 halves = 40960 B.
// Swizzle (halves): idx = row*W + (col ^ ((row&7)<<3)).
// ---------------------------------------------------------------------------
__device__ __forceinline__ int kidx(int row, int col) {
  return row * 128 + (col ^ ((row & 7) << 3));
}
__device__ __forceinline__ int vidx(int row, int col) {
  return row * 64 + (col ^ ((row & 7) << 3));
}

__global__ __launch_bounds__(256, 4) void flash_kernel(
    const _Float16* __restrict__ Wh16, const _Float16* __restrict__ WhT16,
    _Float16* __restrict__ Opart16, float* __restrict__ mpart,
    float* __restrict__ lpart) {
  __shared__ __attribute__((aligned(16))) _Float16 lds[20480];  // 40960 B
  _Float16* Ksh  = lds;                     // 64*128  = 8192 halves
  _Float16* Vtsh = lds + 8192;              // 128*64  = 8192
  _Float16* Psh  = lds + 16384;             // 4*16*64 = 4096

  const int tid  = threadIdx.x;
  const int lane = tid & 63;
  const int wave = tid >> 6;
  const int n16  = lane & 15;
  const int quad = lane >> 4;

  const int qbase  = blockIdx.x * BM + wave * 16;
  const int sp     = blockIdx.y;
  const int tstart = (sp * NKT) / NSPLIT;
  const int tend   = ((sp + 1) * NKT) / NSPLIT;
  const int jbase0 = tstart * BN;
  const int jcount = tend - tstart;          // 21 or 22

  // Q fragments (B operand), pre-scaled by log2e (exact: leaky is
  // positively homogeneous, so scale commutes through leaky+max).
  f16x8 qf[4];
#pragma unroll
  for (int c = 0; c < 4; c++) {
    f16x8 v = *(const f16x8*)&Wh16[(size_t)(qbase + n16) * DIM + c * 32 + quad * 8];
    qf[c] = v * (_Float16)LOG2E;
  }

  // staging decomposition (same coverage as r3/r9; swizzled LDS writes)
  const int krow = tid >> 4;
  const int kcol = (tid & 15) * 8;
  const int vrow = tid >> 3;
  const int vcol = (tid & 7) * 8;
  f16x8 kreg[4], vreg[4];
  auto stage_load = [&](int jb) {
#pragma unroll
    for (int rep = 0; rep < 4; rep++)
      kreg[rep] = *(const f16x8*)&Wh16[(size_t)(jb + rep * 16 + krow) * DIM + kcol];
#pragma unroll
    for (int rep = 0; rep < 4; rep++)
      vreg[rep] = *(const f16x8*)&WhT16[(size_t)(rep * 32 + vrow) * SEQ + jb + vcol];
  };
  auto stage_write = [&]() {
#pragma unroll
    for (int rep = 0; rep < 4; rep++)
      *(f16x8*)&Ksh[kidx(rep * 16 + krow, kcol)] = kreg[rep];
#pragma unroll
    for (int rep = 0; rep < 4; rep++)
      *(f16x8*)&Vtsh[vidx(rep * 32 + vrow, vcol)] = vreg[rep];
  };

  // O^T accumulators: o[ct][e] = O[q=n16][d=ct*16+quad*4+e]
  floatx4 o[8];
#pragma unroll
  for (int ct = 0; ct < 8; ct++) o[ct] = (floatx4){0.f, 0.f, 0.f, 0.f};
  float m_run = -1e30f, l_run = 0.f;        // log2-scale running max

  _Float16* Pw = Psh + wave * 1024;         // this wave's 16 x 64 halves

  // prologue: tile 0 staged (latency exposed once)
  stage_load(jbase0);
  stage_write();
  __syncthreads();

  for (int it = 0; it < jcount; it++) {
    // T14: issue next tile's global loads now; ds_write after the
    // post-compute barrier. Latency hides under this tile's compute.
    if (it + 1 < jcount) stage_load(jbase0 + (it + 1) * BN);

    // ---- S^T = K Q^T (log2-scaled): s[t][e] = S'[q=n16][key=t*16+quad*4+e]
    floatx4 s[4];
    __builtin_amdgcn_s_setprio(1);
#pragma unroll
    for (int t = 0; t < 4; t++) {
      s[t] = (floatx4){0.f, 0.f, 0.f, 0.f};
#pragma unroll
      for (int c = 0; c < 4; c++) {
        f16x8 kf = *(const f16x8*)&Ksh[kidx(t * 16 + n16, c * 32 + quad * 8)];
        s[t] = __builtin_amdgcn_mfma_f32_16x16x32_f16(kf, qf[c], s[t], 0, 0, 0);
      }
    }
    __builtin_amdgcn_s_setprio(0);

    // ---- leaky_relu(0.2) = fmax(x, 0.2x) + in-lane max over 16 keys
    float mx = -1e30f;
#pragma unroll
    for (int t = 0; t < 4; t++)
#pragma unroll
      for (int e = 0; e < 4; e++) {
        float v = fmaxf(s[t][e], 0.2f * s[t][e]);
        s[t][e] = v;
        mx = fmaxf(mx, v);
      }
    mx = fmaxf(mx, __shfl_xor(mx, 16, 64));
    mx = fmaxf(mx, __shfl_xor(mx, 32, 64));

    // T13 defer-max (log2 units: 8*log2e): P bounded by 2^11.54 = e^8.
    if (!__all(mx - m_run <= 11.5416f)) {
      float mnew = fmaxf(m_run, mx);
      float al   = exp2f(m_run - mnew);
      m_run = mnew;
      l_run *= al;
#pragma unroll
      for (int ct = 0; ct < 8; ct++)
#pragma unroll
        for (int e = 0; e < 4; e++) o[ct][e] *= al;
    }

    // ---- P = exp2(S' - m'), in-lane row-sum + 2 shfl
    float rs = 0.f;
#pragma unroll
    for (int t = 0; t < 4; t++)
#pragma unroll
      for (int e = 0; e < 4; e++) {
        float p = exp2f(s[t][e] - m_run);
        s[t][e] = p;
        rs += p;
      }
    rs += __shfl_xor(rs, 16, 64);
    rs += __shfl_xor(rs, 32, 64);
    l_run += rs;

    // ---- P -> LDS (swizzled; 4x ds_write_b64), read back A-layout
#pragma unroll
    for (int t = 0; t < 4; t++) {
      f16x4 pw;
      pw[0] = (_Float16)s[t][0]; pw[1] = (_Float16)s[t][1];
      pw[2] = (_Float16)s[t][2]; pw[3] = (_Float16)s[t][3];
      *(f16x4*)&Pw[vidx(n16, t * 16 + quad * 4)] = pw;
    }
    asm volatile("s_waitcnt lgkmcnt(0)" ::: "memory");
    f16x8 pb[2];
#pragma unroll
    for (int c = 0; c < 2; c++)
      pb[c] = *(const f16x8*)&Pw[vidx(n16, c * 32 + quad * 8)];

    // ---- O^T += V^T P^T
    __builtin_amdgcn_s_setprio(1);
#pragma unroll
    for (int ct = 0; ct < 8; ct++)
#pragma unroll
      for (int c = 0; c < 2; c++) {
        f16x8 vf = *(const f16x8*)&Vtsh[vidx(ct * 16 + n16, c * 32 + quad * 8)];
        o[ct] = __builtin_amdgcn_mfma_f32_16x16x32_f16(vf, pb[c], o[ct], 0, 0, 0);
      }
    __builtin_amdgcn_s_setprio(0);

    __syncthreads();                       // all waves done reading tile it
    if (it + 1 < jcount) {
      stage_write();                       // compiler inserts vmcnt waits
      __syncthreads();                     // tile it+1 ready
    }
  }

  // ---- write NORMALIZED partials O/l as f16 (bounded ~|Wh|max ~ 6)
  float linv = 1.f / l_run;
  _Float16* Op = Opart16 + (size_t)sp * SEQ * DIM;
#pragma unroll
  for (int ct = 0; ct < 8; ct++) {
    f16x4 ov;
    ov[0] = (_Float16)(o[ct][0] * linv); ov[1] = (_Float16)(o[ct][1] * linv);
    ov[2] = (_Float16)(o[ct][2] * linv); ov[3] = (_Float16)(o[ct][3] * linv);
    *(f16x4*)&Op[(size_t)(qbase + n16) * DIM + ct * 16 + quad * 4] = ov;
  }
  if (quad == 0) {
    mpart[sp * SEQ + qbase + n16] = m_run;   // log2-scale
    lpart[sp * SEQ + qbase + n16] = l_run;
  }
}

// ---------------------------------------------------------------------------
// Kernel 3: combine normalized partials (log2-scale m): w_p = 2^(m_p-M) * l_p
// ---------------------------------------------------------------------------
__global__ __launch_bounds__(256) void combine_kernel(
    const _Float16* __restrict__ Opart16, const float* __restrict__ mpart,
    const float* __restrict__ lpart, float* __restrict__ out) {
  int idx4 = blockIdx.x * 256 + threadIdx.x;   // 0 .. SEQ*DIM/4-1
  int row  = idx4 >> 5;                        // 32 four-element chunks per row
  float M = -1e30f;
#pragma unroll
  for (int p = 0; p < NSPLIT; p++) M = fmaxf(M, mpart[p * SEQ + row]);
  float den = 0.f;
  float4 num = make_float4(0.f, 0.f, 0.f, 0.f);
#pragma unroll
  for (int p = 0; p < NSPLIT; p++) {
    float w = exp2f(mpart[p * SEQ + row] - M) * lpart[p * SEQ + row];
    f16x4 v = *(const f16x4*)&Opart16[(size_t)p * SEQ * DIM + (size_t)idx4 * 4];
    num.x += w * (float)v[0]; num.y += w * (float)v[1];
    num.z += w * (float)v[2]; num.w += w * (float)v[3];
    den += w;
  }
  float inv = 1.f / den;
  ((float4*)out)[idx4] = make_float4(num.x * inv, num.y * inv,
                                     num.z * inv, num.w * inv);
}

// ---------------------------------------------------------------------------
extern "C" void kernel_launch(void* const* d_in, const int* in_sizes, int n_in,
                              void* d_out, int out_size, void* d_ws,
                              size_t ws_size, hipStream_t stream) {
  const float* h = (const float*)d_in[0];
  // d_in[1] = adj  (unused by the reference math)
  const float* W = (const float*)d_in[2];
  float* out = (float*)d_out;

  char* ws = (char*)d_ws;
  _Float16* Wh16    = (_Float16*)ws;                               // 2 MiB
  _Float16* WhT16   = (_Float16*)(ws + (size_t)2 * 1024 * 1024);   // 2 MiB
  _Float16* Opart16 = (_Float16*)(ws + (size_t)4 * 1024 * 1024);   // 12 MiB
  float* mpart = (float*)(ws + (size_t)16 * 1024 * 1024);          // 192 KiB
  float* lpart = (float*)(ws + (size_t)16 * 1024 * 1024 + 256 * 1024);
  _Float16* Wt16 = (_Float16*)(ws + (size_t)17 * 1024 * 1024);     // 64 KiB

  wprep_kernel<<<16, 256, 0, stream>>>(W, Wt16);
  wh_kernel<<<SEQ / 16, 256, 0, stream>>>(h, Wt16, Wh16, WhT16);
  dim3 grid(SEQ / BM, NSPLIT);
  flash_kernel<<<grid, 256, 0, stream>>>(Wh16, WhT16, Opart16, mpart, lpart);
  combine_kernel<<<(SEQ * DIM / 4) / 256, 256, 0, stream>>>(Opart16, mpart, lpart, out);
}

// Round 11
// 378.138 us; speedup vs baseline: 1.0274x; 1.0274x over previous
//
#include <hip/hip_runtime.h>

// GAT self-attention: Wh = h@W; out = softmax(leaky_relu(Wh@Wh^T)) @ Wh
// N=8192, IN_F=256, OUT_F=128. adj input unused by the math.
//
// Round 11: r9 structure VERBATIM (measured best, 372.5us: padded LDS,
// launch_bounds(256,3), MFMA wh, f16 normalized partials) + the one
// salvageable r10 piece: exp2-fold (qf pre-scaled by log2e once; softmax
// uses raw v_exp2; defer threshold and combine in log2 units). r10's
// 4-blocks/CU + swizzle is reverted: launch_bounds(256,4) forced 128 VGPRs
// -> scratch spills in the K-loop (+16us).

#define SEQ   8192
#define DIM   128
#define IN_F  256
#define BM    64
#define BN    64
#define NSPLIT 6
#define NKT   (SEQ / BN)      // 128 key tiles total
#define LOG2E 1.4426950408889634f

typedef __attribute__((ext_vector_type(8))) _Float16 f16x8;
typedef __attribute__((ext_vector_type(4))) _Float16 f16x4;
typedef __attribute__((ext_vector_type(4))) float   floatx4;

// ---------------------------------------------------------------------------
// Kernel 0: Wt16[d][k] = (f16) W[k][d].  4096 units of (d, 8-k chunk).
// ---------------------------------------------------------------------------
__global__ __launch_bounds__(256) void wprep_kernel(
    const float* __restrict__ W, _Float16* __restrict__ Wt16) {
  int u = blockIdx.x * 256 + threadIdx.x;     // 0..4095
  int d  = u >> 5;
  int k8 = (u & 31) * 8;
  f16x8 v;
#pragma unroll
  for (int i = 0; i < 8; i++) v[i] = (_Float16)W[(size_t)(k8 + i) * DIM + d];
  *(f16x8*)&Wt16[(size_t)d * IN_F + k8] = v;
}

// ---------------------------------------------------------------------------
// Kernel 1: Wh = h @ W via mfma_f32_16x16x32_f16, dual orientation (r9).
// ---------------------------------------------------------------------------
__global__ __launch_bounds__(256) void wh_kernel(
    const float* __restrict__ h, const _Float16* __restrict__ Wt16,
    _Float16* __restrict__ Wh16, _Float16* __restrict__ WhT16) {
  const int tid  = threadIdx.x;
  const int lane = tid & 63;
  const int wave = tid >> 6;
  const int n16  = lane & 15;
  const int quad = lane >> 4;
  const int qbase = blockIdx.x * 16;

  f16x8 hf[8];
  const float* hrow = h + (size_t)(qbase + n16) * IN_F + quad * 8;
#pragma unroll
  for (int c = 0; c < 8; c++) {
    float4 a = *(const float4*)&hrow[c * 32];
    float4 b = *(const float4*)&hrow[c * 32 + 4];
    f16x8 v;
    v[0] = (_Float16)a.x; v[1] = (_Float16)a.y;
    v[2] = (_Float16)a.z; v[3] = (_Float16)a.w;
    v[4] = (_Float16)b.x; v[5] = (_Float16)b.y;
    v[6] = (_Float16)b.z; v[7] = (_Float16)b.w;
    hf[c] = v;
  }

#pragma unroll
  for (int ti = 0; ti < 2; ti++) {
    const int t = wave * 2 + ti;
    floatx4 o  = (floatx4){0.f, 0.f, 0.f, 0.f};
    floatx4 o2 = (floatx4){0.f, 0.f, 0.f, 0.f};
#pragma unroll
    for (int c = 0; c < 8; c++) {
      f16x8 wf = *(const f16x8*)&Wt16[(size_t)(t * 16 + n16) * IN_F
                                      + c * 32 + quad * 8];
      o  = __builtin_amdgcn_mfma_f32_16x16x32_f16(wf, hf[c], o,  0, 0, 0);
      o2 = __builtin_amdgcn_mfma_f32_16x16x32_f16(hf[c], wf, o2, 0, 0, 0);
    }
    f16x4 r;
    r[0] = (_Float16)o[0]; r[1] = (_Float16)o[1];
    r[2] = (_Float16)o[2]; r[3] = (_Float16)o[3];
    *(f16x4*)&Wh16[(size_t)(qbase + n16) * DIM + t * 16 + quad * 4] = r;
    f16x4 rt;
    rt[0] = (_Float16)o2[0]; rt[1] = (_Float16)o2[1];
    rt[2] = (_Float16)o2[2]; rt[3] = (_Float16)o2[3];
    *(f16x4*)&WhT16[(size_t)(t * 16 + n16) * SEQ + qbase + quad * 4] = rt;
  }
}

// ---------------------------------------------------------------------------
// Kernel 2: flash attention, swapped-QK^T form (r9 structure verbatim).
// grid = (128 qtiles, NSPLIT), block = 256 (4 waves); wave w owns Q rows
// [qtile*64 + w*16, +16).
// LDS: Ksh [64][136] + Vtsh [128][72] + Psh [4][16][72] = 22528 halves = 45KB.
// exp2-fold: qf pre-scaled by log2e; m_run/l_run in log2 units.
// Epilogue: writes O/l as f16 (normalized partials), m (log2) / l fp32.
// ---------------------------------------------------------------------------
__global__ __launch_bounds__(256, 3) void flash_kernel(
    const _Float16* __restrict__ Wh16, const _Float16* __restrict__ WhT16,
    _Float16* __restrict__ Opart16, float* __restrict__ mpart,
    float* __restrict__ lpart) {
  __shared__ _Float16 lds[22528];           // 45056 B
  _Float16* Ksh  = lds;                     // 64*136  = 8704 halves
  _Float16* Vtsh = lds + 8704;              // 128*72  = 9216
  _Float16* Psh  = lds + 8704 + 9216;       // 4*16*72 = 4608

  const int tid  = threadIdx.x;
  const int lane = tid & 63;
  const int wave = tid >> 6;
  const int n16  = lane & 15;
  const int quad = lane >> 4;

  const int qbase  = blockIdx.x * BM + wave * 16;
  const int sp     = blockIdx.y;
  const int tstart = (sp * NKT) / NSPLIT;
  const int tend   = ((sp + 1) * NKT) / NSPLIT;
  const int jbase0 = tstart * BN;
  const int jcount = tend - tstart;          // 21 or 22

  // Q fragments (B operand), pre-scaled by log2e (exact: leaky_relu is
  // positively homogeneous, so the scale commutes through leaky and max).
  f16x8 qf[4];
#pragma unroll
  for (int c = 0; c < 4; c++) {
    f16x8 v = *(const f16x8*)&Wh16[(size_t)(qbase + n16) * DIM + c * 32 + quad * 8];
    qf[c] = v * (_Float16)LOG2E;
  }

  // staging decomposition (identical to r3/r9)
  const int krow = tid >> 4;
  const int kcol = (tid & 15) * 8;
  const int vrow = tid >> 3;
  const int vcol = (tid & 7) * 8;
  f16x8 kreg[4], vreg[4];
  auto stage_load = [&](int jb) {
#pragma unroll
    for (int rep = 0; rep < 4; rep++)
      kreg[rep] = *(const f16x8*)&Wh16[(size_t)(jb + rep * 16 + krow) * DIM + kcol];
#pragma unroll
    for (int rep = 0; rep < 4; rep++)
      vreg[rep] = *(const f16x8*)&WhT16[(size_t)(rep * 32 + vrow) * SEQ + jb + vcol];
  };
  auto stage_write = [&]() {
#pragma unroll
    for (int rep = 0; rep < 4; rep++)
      *(f16x8*)&Ksh[(rep * 16 + krow) * 136 + kcol] = kreg[rep];
#pragma unroll
    for (int rep = 0; rep < 4; rep++)
      *(f16x8*)&Vtsh[(rep * 32 + vrow) * 72 + vcol] = vreg[rep];
  };

  // O^T accumulators: o[ct][e] = O[q=n16][d=ct*16+quad*4+e]
  floatx4 o[8];
#pragma unroll
  for (int ct = 0; ct < 8; ct++) o[ct] = (floatx4){0.f, 0.f, 0.f, 0.f};
  float m_run = -1e30f, l_run = 0.f;        // log2-scale running max / sum

  _Float16* Pw = Psh + wave * 1152;         // this wave's 16 x 72 halves

  // prologue: tile 0 staged (latency exposed once)
  stage_load(jbase0);
  stage_write();
  __syncthreads();

  for (int it = 0; it < jcount; it++) {
    // T14: issue next tile's global loads now; ds_write after the
    // post-compute barrier. Latency hides under this tile's compute.
    if (it + 1 < jcount) stage_load(jbase0 + (it + 1) * BN);

    // ---- S^T = K Q^T (log2-scaled): s[t][e] = S'[q=n16][key=t*16+quad*4+e]
    floatx4 s[4];
    __builtin_amdgcn_s_setprio(1);
#pragma unroll
    for (int t = 0; t < 4; t++) {
      s[t] = (floatx4){0.f, 0.f, 0.f, 0.f};
#pragma unroll
      for (int c = 0; c < 4; c++) {
        f16x8 kf = *(const f16x8*)&Ksh[(t * 16 + n16) * 136 + c * 32 + quad * 8];
        s[t] = __builtin_amdgcn_mfma_f32_16x16x32_f16(kf, qf[c], s[t], 0, 0, 0);
      }
    }
    __builtin_amdgcn_s_setprio(0);

    // ---- leaky_relu(0.2) = fmax(x, 0.2x) + in-lane max over 16 keys
    float mx = -1e30f;
#pragma unroll
    for (int t = 0; t < 4; t++)
#pragma unroll
      for (int e = 0; e < 4; e++) {
        float v = fmaxf(s[t][e], 0.2f * s[t][e]);
        s[t][e] = v;
        mx = fmaxf(mx, v);
      }
    mx = fmaxf(mx, __shfl_xor(mx, 16, 64));
    mx = fmaxf(mx, __shfl_xor(mx, 32, 64));

    // T13 defer-max (log2 units: 8*log2e): P bounded by 2^11.54 = e^8.
    if (!__all(mx - m_run <= 11.5416f)) {
      float mnew = fmaxf(m_run, mx);
      float al   = exp2f(m_run - mnew);
      m_run = mnew;
      l_run *= al;
#pragma unroll
      for (int ct = 0; ct < 8; ct++)
#pragma unroll
        for (int e = 0; e < 4; e++) o[ct][e] *= al;
    }

    // ---- P = exp2(S' - m'), in-lane row-sum + 2 shfl
    float rs = 0.f;
#pragma unroll
    for (int t = 0; t < 4; t++)
#pragma unroll
      for (int e = 0; e < 4; e++) {
        float p = exp2f(s[t][e] - m_run);
        s[t][e] = p;
        rs += p;
      }
    rs += __shfl_xor(rs, 16, 64);
    rs += __shfl_xor(rs, 32, 64);
    l_run += rs;

    // ---- P -> LDS (e-contiguous: 4x ds_write_b64), read back A-layout
#pragma unroll
    for (int t = 0; t < 4; t++) {
      f16x4 pw;
      pw[0] = (_Float16)s[t][0]; pw[1] = (_Float16)s[t][1];
      pw[2] = (_Float16)s[t][2]; pw[3] = (_Float16)s[t][3];
      *(f16x4*)&Pw[n16 * 72 + t * 16 + quad * 4] = pw;
    }
    asm volatile("s_waitcnt lgkmcnt(0)" ::: "memory");
    f16x8 pb[2];
#pragma unroll
    for (int c = 0; c < 2; c++)
      pb[c] = *(const f16x8*)&Pw[n16 * 72 + c * 32 + quad * 8];

    // ---- O^T += V^T P^T
    __builtin_amdgcn_s_setprio(1);
#pragma unroll
    for (int ct = 0; ct < 8; ct++)
#pragma unroll
      for (int c = 0; c < 2; c++) {
        f16x8 vf = *(const f16x8*)&Vtsh[(ct * 16 + n16) * 72 + c * 32 + quad * 8];
        o[ct] = __builtin_amdgcn_mfma_f32_16x16x32_f16(vf, pb[c], o[ct], 0, 0, 0);
      }
    __builtin_amdgcn_s_setprio(0);

    __syncthreads();                       // all waves done reading tile it
    if (it + 1 < jcount) {
      stage_write();                       // compiler inserts vmcnt waits
      __syncthreads();                     // tile it+1 ready
    }
  }

  // ---- write NORMALIZED partials O/l as f16 (bounded ~|Wh|max ~ 6)
  float linv = 1.f / l_run;
  _Float16* Op = Opart16 + (size_t)sp * SEQ * DIM;
#pragma unroll
  for (int ct = 0; ct < 8; ct++) {
    f16x4 ov;
    ov[0] = (_Float16)(o[ct][0] * linv); ov[1] = (_Float16)(o[ct][1] * linv);
    ov[2] = (_Float16)(o[ct][2] * linv); ov[3] = (_Float16)(o[ct][3] * linv);
    *(f16x4*)&Op[(size_t)(qbase + n16) * DIM + ct * 16 + quad * 4] = ov;
  }
  if (quad == 0) {
    mpart[sp * SEQ + qbase + n16] = m_run;   // log2-scale
    lpart[sp * SEQ + qbase + n16] = l_run;
  }
}

// ---------------------------------------------------------------------------
// Kernel 3: combine normalized partials (log2-scale m): w_p = 2^(m_p-M) * l_p
// ---------------------------------------------------------------------------
__global__ __launch_bounds__(256) void combine_kernel(
    const _Float16* __restrict__ Opart16, const float* __restrict__ mpart,
    const float* __restrict__ lpart, float* __restrict__ out) {
  int idx4 = blockIdx.x * 256 + threadIdx.x;   // 0 .. SEQ*DIM/4-1
  int row  = idx4 >> 5;                        // 32 four-element chunks per row
  float M = -1e30f;
#pragma unroll
  for (int p = 0; p < NSPLIT; p++) M = fmaxf(M, mpart[p * SEQ + row]);
  float den = 0.f;
  float4 num = make_float4(0.f, 0.f, 0.f, 0.f);
#pragma unroll
  for (int p = 0; p < NSPLIT; p++) {
    float w = exp2f(mpart[p * SEQ + row] - M) * lpart[p * SEQ + row];
    f16x4 v = *(const f16x4*)&Opart16[(size_t)p * SEQ * DIM + (size_t)idx4 * 4];
    num.x += w * (float)v[0]; num.y += w * (float)v[1];
    num.z += w * (float)v[2]; num.w += w * (float)v[3];
    den += w;
  }
  float inv = 1.f / den;
  ((float4*)out)[idx4] = make_float4(num.x * inv, num.y * inv,
                                     num.z * inv, num.w * inv);
}

// ---------------------------------------------------------------------------
extern "C" void kernel_launch(void* const* d_in, const int* in_sizes, int n_in,
                              void* d_out, int out_size, void* d_ws,
                              size_t ws_size, hipStream_t stream) {
  const float* h = (const float*)d_in[0];
  // d_in[1] = adj  (unused by the reference math)
  const float* W = (const float*)d_in[2];
  float* out = (float*)d_out;

  char* ws = (char*)d_ws;
  _Float16* Wh16    = (_Float16*)ws;                               // 2 MiB
  _Float16* WhT16   = (_Float16*)(ws + (size_t)2 * 1024 * 1024);   // 2 MiB
  _Float16* Opart16 = (_Float16*)(ws + (size_t)4 * 1024 * 1024);   // 12 MiB
  float* mpart = (float*)(ws + (size_t)16 * 1024 * 1024);          // 192 KiB
  float* lpart = (float*)(ws + (size_t)16 * 1024 * 1024 + 256 * 1024);
  _Float16* Wt16 = (_Float16*)(ws + (size_t)17 * 1024 * 1024);     // 64 KiB

  wprep_kernel<<<16, 256, 0, stream>>>(W, Wt16);
  wh_kernel<<<SEQ / 16, 256, 0, stream>>>(h, Wt16, Wh16, WhT16);
  dim3 grid(SEQ / BM, NSPLIT);
  flash_kernel<<<grid, 256, 0, stream>>>(Wh16, WhT16, Opart16, mpart, lpart);
  combine_kernel<<<(SEQ * DIM / 4) / 256, 256, 0, stream>>>(Opart16, mpart, lpart, out);
}

// Round 12
// 372.763 us; speedup vs baseline: 1.0422x; 1.0144x over previous
//
#include <hip/hip_runtime.h>

// GAT self-attention: Wh = h@W; out = softmax(leaky_relu(Wh@Wh^T)) @ Wh
// N=8192, IN_F=256, OUT_F=128. adj input unused by the math.
//
// FINAL (= round 9 verbatim, best measured 372.5us):
//  - wprep: W fp32 -> Wt16 = W^T f16 (64 KB, L2-hot)
//  - wh: MFMA dual-orientation (o = mfma(wf,hf) -> Wh16; o2 = mfma(hf,wf)
//    -> WhT16), both with coalesced f16x4 stores.
//  - flash: swapped-QK^T (lane-local softmax), padded LDS (K[64][136],
//    Vt[128][72], P[4][16][72]), T14 one-tile-ahead reg prefetch,
//    3 blocks/CU, defer-max (T13), setprio (T5), f16 normalized partials.
//  - combine: log-sum-exp weighted merge of NSPLIT f16 partials.
// Session ledger: timed window ~= 322us harness fills (2 x 1GiB memset at
// ~83% HBM peak, immovable) + ~50us kernels (flash ~40, wh ~4, combine ~4).
// Perturbations in every direction regressed (r4, r6, r10, r11).

#define SEQ   8192
#define DIM   128
#define IN_F  256
#define BM    64
#define BN    64
#define NSPLIT 6
#define NKT   (SEQ / BN)      // 128 key tiles total

typedef __attribute__((ext_vector_type(8))) _Float16 f16x8;
typedef __attribute__((ext_vector_type(4))) _Float16 f16x4;
typedef __attribute__((ext_vector_type(4))) float   floatx4;

// ---------------------------------------------------------------------------
// Kernel 0: Wt16[d][k] = (f16) W[k][d].  4096 units of (d, 8-k chunk).
// ---------------------------------------------------------------------------
__global__ __launch_bounds__(256) void wprep_kernel(
    const float* __restrict__ W, _Float16* __restrict__ Wt16) {
  int u = blockIdx.x * 256 + threadIdx.x;     // 0..4095
  int d  = u >> 5;
  int k8 = (u & 31) * 8;
  f16x8 v;
#pragma unroll
  for (int i = 0; i < 8; i++) v[i] = (_Float16)W[(size_t)(k8 + i) * DIM + d];
  *(f16x8*)&Wt16[(size_t)d * IN_F + k8] = v;
}

// ---------------------------------------------------------------------------
// Kernel 1: Wh = h @ W via mfma_f32_16x16x32_f16, dual orientation.
// 512 blocks x 16 q-rows; wave w owns d-tiles {2w, 2w+1}.
//   o  = mfma(wf, hf): lane(n16,quad) e -> Wh[qbase+n16][t*16+quad*4+e]
//   o2 = mfma(hf, wf): lane(n16,quad) e -> Wh[qbase+quad*4+e][t*16+n16]
// ---------------------------------------------------------------------------
__global__ __launch_bounds__(256) void wh_kernel(
    const float* __restrict__ h, const _Float16* __restrict__ Wt16,
    _Float16* __restrict__ Wh16, _Float16* __restrict__ WhT16) {
  const int tid  = threadIdx.x;
  const int lane = tid & 63;
  const int wave = tid >> 6;
  const int n16  = lane & 15;
  const int quad = lane >> 4;
  const int qbase = blockIdx.x * 16;

  // hf[c] = (f16) h[qbase+n16][c*32 + quad*8 .. +7]
  f16x8 hf[8];
  const float* hrow = h + (size_t)(qbase + n16) * IN_F + quad * 8;
#pragma unroll
  for (int c = 0; c < 8; c++) {
    float4 a = *(const float4*)&hrow[c * 32];
    float4 b = *(const float4*)&hrow[c * 32 + 4];
    f16x8 v;
    v[0] = (_Float16)a.x; v[1] = (_Float16)a.y;
    v[2] = (_Float16)a.z; v[3] = (_Float16)a.w;
    v[4] = (_Float16)b.x; v[5] = (_Float16)b.y;
    v[6] = (_Float16)b.z; v[7] = (_Float16)b.w;
    hf[c] = v;
  }

#pragma unroll
  for (int ti = 0; ti < 2; ti++) {
    const int t = wave * 2 + ti;
    floatx4 o  = (floatx4){0.f, 0.f, 0.f, 0.f};
    floatx4 o2 = (floatx4){0.f, 0.f, 0.f, 0.f};
#pragma unroll
    for (int c = 0; c < 8; c++) {
      f16x8 wf = *(const f16x8*)&Wt16[(size_t)(t * 16 + n16) * IN_F
                                      + c * 32 + quad * 8];
      o  = __builtin_amdgcn_mfma_f32_16x16x32_f16(wf, hf[c], o,  0, 0, 0);
      o2 = __builtin_amdgcn_mfma_f32_16x16x32_f16(hf[c], wf, o2, 0, 0, 0);
    }
    f16x4 r;
    r[0] = (_Float16)o[0]; r[1] = (_Float16)o[1];
    r[2] = (_Float16)o[2]; r[3] = (_Float16)o[3];
    *(f16x4*)&Wh16[(size_t)(qbase + n16) * DIM + t * 16 + quad * 4] = r;
    f16x4 rt;
    rt[0] = (_Float16)o2[0]; rt[1] = (_Float16)o2[1];
    rt[2] = (_Float16)o2[2]; rt[3] = (_Float16)o2[3];
    *(f16x4*)&WhT16[(size_t)(t * 16 + n16) * SEQ + qbase + quad * 4] = rt;
  }
}

// ---------------------------------------------------------------------------
// Kernel 2: flash attention, swapped-QK^T form.
// grid = (128 qtiles, NSPLIT), block = 256 (4 waves); wave w owns Q rows
// [qtile*64 + w*16, +16).
// LDS: Ksh [64][136] + Vtsh [128][72] + Psh [4][16][72] = 22528 halves = 45KB.
// Epilogue: writes O/l as f16 (normalized partials), m/l fp32.
// ---------------------------------------------------------------------------
__global__ __launch_bounds__(256, 3) void flash_kernel(
    const _Float16* __restrict__ Wh16, const _Float16* __restrict__ WhT16,
    _Float16* __restrict__ Opart16, float* __restrict__ mpart,
    float* __restrict__ lpart) {
  __shared__ _Float16 lds[22528];           // 45056 B
  _Float16* Ksh  = lds;                     // 64*136  = 8704 halves
  _Float16* Vtsh = lds + 8704;              // 128*72  = 9216
  _Float16* Psh  = lds + 8704 + 9216;       // 4*16*72 = 4608

  const int tid  = threadIdx.x;
  const int lane = tid & 63;
  const int wave = tid >> 6;
  const int n16  = lane & 15;
  const int quad = lane >> 4;

  const int qbase  = blockIdx.x * BM + wave * 16;
  const int sp     = blockIdx.y;
  const int tstart = (sp * NKT) / NSPLIT;
  const int tend   = ((sp + 1) * NKT) / NSPLIT;
  const int jbase0 = tstart * BN;
  const int jcount = tend - tstart;          // 21 or 22

  // Q fragments (B operand): qf[c] = Q[qbase+n16][c*32+quad*8+j]
  f16x8 qf[4];
#pragma unroll
  for (int c = 0; c < 4; c++)
    qf[c] = *(const f16x8*)&Wh16[(size_t)(qbase + n16) * DIM + c * 32 + quad * 8];

  // staging decomposition (identical to r2/r3)
  const int krow = tid >> 4;
  const int kcol = (tid & 15) * 8;
  const int vrow = tid >> 3;
  const int vcol = (tid & 7) * 8;
  f16x8 kreg[4], vreg[4];
  auto stage_load = [&](int jb) {
#pragma unroll
    for (int rep = 0; rep < 4; rep++)
      kreg[rep] = *(const f16x8*)&Wh16[(size_t)(jb + rep * 16 + krow) * DIM + kcol];
#pragma unroll
    for (int rep = 0; rep < 4; rep++)
      vreg[rep] = *(const f16x8*)&WhT16[(size_t)(rep * 32 + vrow) * SEQ + jb + vcol];
  };
  auto stage_write = [&]() {
#pragma unroll
    for (int rep = 0; rep < 4; rep++)
      *(f16x8*)&Ksh[(rep * 16 + krow) * 136 + kcol] = kreg[rep];
#pragma unroll
    for (int rep = 0; rep < 4; rep++)
      *(f16x8*)&Vtsh[(rep * 32 + vrow) * 72 + vcol] = vreg[rep];
  };

  // O^T accumulators: o[ct][e] = O[q=n16][d=ct*16+quad*4+e]
  floatx4 o[8];
#pragma unroll
  for (int ct = 0; ct < 8; ct++) o[ct] = (floatx4){0.f, 0.f, 0.f, 0.f};
  float m_run = -1e30f, l_run = 0.f;        // per-lane scalars (row q = n16)

  _Float16* Pw = Psh + wave * 1152;         // this wave's 16 x 72 halves

  // prologue: tile 0 staged (latency exposed once)
  stage_load(jbase0);
  stage_write();
  __syncthreads();

  for (int it = 0; it < jcount; it++) {
    // T14: issue next tile's global loads now; ds_write after the
    // post-compute barrier. Latency hides under this tile's compute.
    if (it + 1 < jcount) stage_load(jbase0 + (it + 1) * BN);

    // ---- S^T = K Q^T : s[t][e] = S[q=n16][key = t*16 + quad*4 + e]
    floatx4 s[4];
    __builtin_amdgcn_s_setprio(1);
#pragma unroll
    for (int t = 0; t < 4; t++) {
      s[t] = (floatx4){0.f, 0.f, 0.f, 0.f};
#pragma unroll
      for (int c = 0; c < 4; c++) {
        f16x8 kf = *(const f16x8*)&Ksh[(t * 16 + n16) * 136 + c * 32 + quad * 8];
        s[t] = __builtin_amdgcn_mfma_f32_16x16x32_f16(kf, qf[c], s[t], 0, 0, 0);
      }
    }
    __builtin_amdgcn_s_setprio(0);

    // ---- leaky_relu(0.2) = fmax(x, 0.2x) + in-lane max over 16 keys
    float mx = -1e30f;
#pragma unroll
    for (int t = 0; t < 4; t++)
#pragma unroll
      for (int e = 0; e < 4; e++) {
        float v = fmaxf(s[t][e], 0.2f * s[t][e]);
        s[t][e] = v;
        mx = fmaxf(mx, v);
      }
    mx = fmaxf(mx, __shfl_xor(mx, 16, 64));
    mx = fmaxf(mx, __shfl_xor(mx, 32, 64));

    // T13 defer-max: skip O/l rescale while tile max <= running max + 8.
    // P then bounded by e^8 ~ 2981, inside f16 range.
    if (!__all(mx - m_run <= 8.f)) {
      float mnew = fmaxf(m_run, mx);
      float al   = __expf(m_run - mnew);
      m_run = mnew;
      l_run *= al;
#pragma unroll
      for (int ct = 0; ct < 8; ct++)
#pragma unroll
        for (int e = 0; e < 4; e++) o[ct][e] *= al;
    }

    // ---- P = exp(S - m), in-lane row-sum + 2 shfl
    float rs = 0.f;
#pragma unroll
    for (int t = 0; t < 4; t++)
#pragma unroll
      for (int e = 0; e < 4; e++) {
        float p = __expf(s[t][e] - m_run);
        s[t][e] = p;
        rs += p;
      }
    rs += __shfl_xor(rs, 16, 64);
    rs += __shfl_xor(rs, 32, 64);
    l_run += rs;

    // ---- P -> LDS (e-contiguous: 4x ds_write_b64), read back A-layout
#pragma unroll
    for (int t = 0; t < 4; t++) {
      f16x4 pw;
      pw[0] = (_Float16)s[t][0]; pw[1] = (_Float16)s[t][1];
      pw[2] = (_Float16)s[t][2]; pw[3] = (_Float16)s[t][3];
      *(f16x4*)&Pw[n16 * 72 + t * 16 + quad * 4] = pw;
    }
    asm volatile("s_waitcnt lgkmcnt(0)" ::: "memory");
    f16x8 pb[2];
#pragma unroll
    for (int c = 0; c < 2; c++)
      pb[c] = *(const f16x8*)&Pw[n16 * 72 + c * 32 + quad * 8];

    // ---- O^T += V^T P^T
    __builtin_amdgcn_s_setprio(1);
#pragma unroll
    for (int ct = 0; ct < 8; ct++)
#pragma unroll
      for (int c = 0; c < 2; c++) {
        f16x8 vf = *(const f16x8*)&Vtsh[(ct * 16 + n16) * 72 + c * 32 + quad * 8];
        o[ct] = __builtin_amdgcn_mfma_f32_16x16x32_f16(vf, pb[c], o[ct], 0, 0, 0);
      }
    __builtin_amdgcn_s_setprio(0);

    __syncthreads();                       // all waves done reading tile it
    if (it + 1 < jcount) {
      stage_write();                       // compiler inserts vmcnt waits
      __syncthreads();                     // tile it+1 ready
    }
  }

  // ---- write NORMALIZED partials O/l as f16 (bounded ~|Wh|max ~ 6)
  float linv = 1.f / l_run;
  _Float16* Op = Opart16 + (size_t)sp * SEQ * DIM;
#pragma unroll
  for (int ct = 0; ct < 8; ct++) {
    f16x4 ov;
    ov[0] = (_Float16)(o[ct][0] * linv); ov[1] = (_Float16)(o[ct][1] * linv);
    ov[2] = (_Float16)(o[ct][2] * linv); ov[3] = (_Float16)(o[ct][3] * linv);
    *(f16x4*)&Op[(size_t)(qbase + n16) * DIM + ct * 16 + quad * 4] = ov;
  }
  if (quad == 0) {
    mpart[sp * SEQ + qbase + n16] = m_run;
    lpart[sp * SEQ + qbase + n16] = l_run;
  }
}

// ---------------------------------------------------------------------------
// Kernel 3: combine normalized partials: out = sum_p w_p*(O_p/l_p) / sum_p w_p
// with w_p = exp(m_p - M) * l_p. f16x4 loads, float4 store.
// ---------------------------------------------------------------------------
__global__ __launch_bounds__(256) void combine_kernel(
    const _Float16* __restrict__ Opart16, const float* __restrict__ mpart,
    const float* __restrict__ lpart, float* __restrict__ out) {
  int idx4 = blockIdx.x * 256 + threadIdx.x;   // 0 .. SEQ*DIM/4-1
  int row  = idx4 >> 5;                        // 32 four-element chunks per row
  float M = -1e30f;
#pragma unroll
  for (int p = 0; p < NSPLIT; p++) M = fmaxf(M, mpart[p * SEQ + row]);
  float den = 0.f;
  float4 num = make_float4(0.f, 0.f, 0.f, 0.f);
#pragma unroll
  for (int p = 0; p < NSPLIT; p++) {
    float w = __expf(mpart[p * SEQ + row] - M) * lpart[p * SEQ + row];
    f16x4 v = *(const f16x4*)&Opart16[(size_t)p * SEQ * DIM + (size_t)idx4 * 4];
    num.x += w * (float)v[0]; num.y += w * (float)v[1];
    num.z += w * (float)v[2]; num.w += w * (float)v[3];
    den += w;
  }
  float inv = 1.f / den;
  ((float4*)out)[idx4] = make_float4(num.x * inv, num.y * inv,
                                     num.z * inv, num.w * inv);
}

// ---------------------------------------------------------------------------
extern "C" void kernel_launch(void* const* d_in, const int* in_sizes, int n_in,
                              void* d_out, int out_size, void* d_ws,
                              size_t ws_size, hipStream_t stream) {
  const float* h = (const float*)d_in[0];
  // d_in[1] = adj  (unused by the reference math)
  const float* W = (const float*)d_in[2];
  float* out = (float*)d_out;

  char* ws = (char*)d_ws;
  _Float16* Wh16    = (_Float16*)ws;                               // 2 MiB
  _Float16* WhT16   = (_Float16*)(ws + (size_t)2 * 1024 * 1024);   // 2 MiB
  _Float16* Opart16 = (_Float16*)(ws + (size_t)4 * 1024 * 1024);   // 12 MiB
  float* mpart = (float*)(ws + (size_t)16 * 1024 * 1024);          // 192 KiB
  float* lpart = (float*)(ws + (size_t)16 * 1024 * 1024 + 256 * 1024);
  _Float16* Wt16 = (_Float16*)(ws + (size_t)17 * 1024 * 1024);     // 64 KiB

  wprep_kernel<<<16, 256, 0, stream>>>(W, Wt16);
  wh_kernel<<<SEQ / 16, 256, 0, stream>>>(h, Wt16, Wh16, WhT16);
  dim3 grid(SEQ / BM, NSPLIT);
  flash_kernel<<<grid, 256, 0, stream>>>(Wh16, WhT16, Opart16, mpart, lpart);
  combine_kernel<<<(SEQ * DIM / 4) / 256, 256, 0, stream>>>(Opart16, mpart, lpart, out);
}